// Round 6
// baseline (433.325 us; speedup 1.0000x reference)
//
#include <hip/hip_runtime.h>
#include <hip/hip_cooperative_groups.h>
#include <stdint.h>

namespace cg = cooperative_groups;

#define N_EXPERTS 8
#define IN_DIM    1024
#define OUT_DIM   1024
#define N_TOKENS  16384
#define S_SLOTS   (N_TOKENS * 2)
#define BM 128
#define BN 128
#define BK 32
#define MAX_TILES 264   // sum ceil(cnt_e/128) <= 256 + 8
#define NGROUPS   (OUT_DIM / BN)   // 8

typedef unsigned short u16;
using short4v = __attribute__((ext_vector_type(4))) short;
using short8  = __attribute__((ext_vector_type(8))) short;
using f32x4   = __attribute__((ext_vector_type(4))) float;

__device__ __forceinline__ u16 f2bf(float f) {
  uint32_t x = __builtin_bit_cast(uint32_t, f);
  uint32_t r = x + 0x7fffu + ((x >> 16) & 1u);   // round-to-nearest-even
  return (u16)(r >> 16);
}
__device__ __forceinline__ float bf2f(u16 u) {
  uint32_t x = ((uint32_t)u) << 16;
  return __builtin_bit_cast(float, x);
}

#define GLD_LDS16(g, l) __builtin_amdgcn_global_load_lds(            \
    (const __attribute__((address_space(1))) void*)(g),              \
    (__attribute__((address_space(3))) void*)(l), 16, 0, 0)

// ---------------------------------------------------------------------------
// Shared tile derivation (slots sorted by expert; <=264 M-tiles)
// ---------------------------------------------------------------------------
__device__ __forceinline__ bool derive_tile(const int* eoff_raw, bool is64,
                                            int bx, int& expert, int& rs, int& re) {
  int rem = bx, prev = 0;
  expert = -1;
  for (int e = 0; e < N_EXPERTS; ++e) {
    int end = is64 ? eoff_raw[2 * e] : eoff_raw[e];
    int cnt = end - prev;
    int nt  = (cnt + BM - 1) / BM;
    if (expert < 0) {
      if (rem < nt) {
        expert = e;
        rs = prev + rem * BM;
        re = (rs + BM < end) ? (rs + BM) : end;
      } else {
        rem -= nt;
      }
    }
    prev = end;
  }
  return expert >= 0;
}

// ---------------------------------------------------------------------------
// ONE persistent cooperative kernel: convert -> sync -> grouped GEMM -> sync
// -> gate combine. Eliminates per-dispatch-node overhead (~30-40us x2).
// ---------------------------------------------------------------------------
__global__ __launch_bounds__(256, 4) void moe_fused(
    const float* __restrict__ X,        // [N_TOKENS, IN_DIM] fp32
    const float* __restrict__ W,        // [E, OUT_DIM, IN_DIM] fp32
    const float* __restrict__ gates,    // [S] fp32
    const int*   __restrict__ kptr,
    const int*   __restrict__ ssi_raw,  // int32 or int64
    const int*   __restrict__ eoff_raw, // int32 or int64
    u16* __restrict__ Xb, u16* __restrict__ Wb,
    u16* __restrict__ slot_out,         // [S, OUT_DIM] bf16 (ws)
    float* __restrict__ out,            // [N_TOKENS, OUT_DIM] fp32
    int nblk)
{
  __shared__ __align__(16) u16 smem[BM * BN];   // 32 KB
  cg::grid_group grid = cg::this_grid();

  const int bid = blockIdx.x;
  const int t   = threadIdx.x;

  // ---------------- Phase A: fp32 -> bf16 convert of X and W --------------
  const int xn8  = (N_TOKENS * IN_DIM) / 8;              // 2,097,152
  const int wn8  = (N_EXPERTS * OUT_DIM * IN_DIM) / 8;   // 1,048,576
  const int tot8 = xn8 + wn8;
  for (int i = bid * 256 + t; i < tot8; i += nblk * 256) {
    const float* src; u16* dst; int j;
    if (i < xn8) { src = X; dst = Xb; j = i; }
    else         { src = W; dst = Wb; j = i - xn8; }
    f32x4 v0 = ((const f32x4*)src)[(size_t)j * 2];
    f32x4 v1 = ((const f32x4*)src)[(size_t)j * 2 + 1];
    short8 o;
#pragma unroll
    for (int q = 0; q < 4; ++q) {
      o[q]     = (short)f2bf(v0[q]);
      o[4 + q] = (short)f2bf(v1[q]);
    }
    *(short8*)(dst + (size_t)j * 8) = o;
  }

  grid.sync();

  // ---------------- Phase B: persistent grouped GEMM ----------------------
  const bool is64 = (eoff_raw[7] != S_SLOTS);
  int ntiles = 0;
  {
    int prev = 0;
    for (int e = 0; e < N_EXPERTS; ++e) {
      int end = is64 ? eoff_raw[2 * e] : eoff_raw[e];
      ntiles += (end - prev + BM - 1) / BM;
      prev = end;
    }
  }
  const int njobs = ntiles * NGROUPS;
  const int kdiv  = kptr[0];

  u16* As = smem;             // BM*BK
  u16* Bs = smem + BM * BK;   // BN*BK

  const int wave = t >> 6;
  const int lane = t & 63;
  const int wm = (wave >> 1) * 64;
  const int wn = (wave & 1) * 64;
  const int lr = lane & 15;
  const int lk = (lane >> 4) * 8;

  // staging map: 512 16B-chunks/slab; thread handles chunks t and t+256.
  const int r0 = t >> 2;
  const int r1 = (t + 256) >> 2;
  const int cg2 = (t & 3) * 8;

  for (int job = bid; job < njobs; job += nblk) {
    int tile = job % ntiles;
    int n0   = (job / ntiles) * BN;

    int expert, rs, re;
    derive_tile(eoff_raw, is64, tile, expert, rs, re);
    const int rcount = re - rs;

    int g0 = rs + r0; if (g0 >= re) g0 = re - 1;
    int g1 = rs + r1; if (g1 >= re) g1 = re - 1;
    const int tok0 = (is64 ? ssi_raw[2 * g0] : ssi_raw[g0]) / kdiv;
    const int tok1 = (is64 ? ssi_raw[2 * g1] : ssi_raw[g1]) / kdiv;

    const u16* a0 = Xb + (size_t)tok0 * IN_DIM + cg2;
    const u16* a1 = Xb + (size_t)tok1 * IN_DIM + cg2;
    const u16* wbp = Wb + (size_t)expert * OUT_DIM * IN_DIM;
    const u16* b0 = wbp + (size_t)(n0 + r0) * IN_DIM + cg2;
    const u16* b1 = wbp + (size_t)(n0 + r1) * IN_DIM + cg2;

    f32x4 acc[4][4];
#pragma unroll
    for (int i = 0; i < 4; ++i)
#pragma unroll
      for (int j = 0; j < 4; ++j)
        acc[i][j] = (f32x4){0.f, 0.f, 0.f, 0.f};

    __syncthreads();   // smem (Cs of previous job) free before restaging

    for (int k0 = 0; k0 < IN_DIM; k0 += BK) {
      GLD_LDS16(a0 + k0, As + (size_t)t * 8);
      GLD_LDS16(a1 + k0, As + (size_t)(t + 256) * 8);
      GLD_LDS16(b0 + k0, Bs + (size_t)t * 8);
      GLD_LDS16(b1 + k0, Bs + (size_t)(t + 256) * 8);
      __syncthreads();   // drains vmcnt -> LDS valid

      short8 af[4], bfv[4];
#pragma unroll
      for (int mi = 0; mi < 4; ++mi)
        af[mi] = *(const short8*)&As[(wm + mi * 16 + lr) * BK + lk];
#pragma unroll
      for (int ni = 0; ni < 4; ++ni)
        bfv[ni] = *(const short8*)&Bs[(wn + ni * 16 + lr) * BK + lk];

#pragma unroll
      for (int mi = 0; mi < 4; ++mi)
#pragma unroll
        for (int ni = 0; ni < 4; ++ni)
          acc[mi][ni] = __builtin_amdgcn_mfma_f32_16x16x32_bf16(
              af[mi], bfv[ni], acc[mi][ni], 0, 0, 0);

      __syncthreads();
    }

    // Epilogue: C layout col=lane&15, row=(lane>>4)*4+reg -> repack -> 16B st
    u16* Cs = smem;
#pragma unroll
    for (int mi = 0; mi < 4; ++mi)
#pragma unroll
      for (int ni = 0; ni < 4; ++ni)
#pragma unroll
        for (int r = 0; r < 4; ++r) {
          int row = wm + mi * 16 + (lane >> 4) * 4 + r;
          int col = wn + ni * 16 + lr;
          Cs[row * BN + col] = f2bf(acc[mi][ni][r]);
        }
    __syncthreads();

    const int crow = t >> 4;
    const int ccol = (t & 15) * 8;
#pragma unroll
    for (int i = 0; i < 8; ++i) {
      int row = i * 16 + crow;
      if (row < rcount) {
        *(short8*)&slot_out[(size_t)(rs + row) * OUT_DIM + n0 + ccol] =
            *(const short8*)&Cs[row * BN + ccol];
      }
    }
  }

  grid.sync();

  // ---------------- Phase C: gate combine ---------------------------------
  const int cchunks = N_TOKENS * OUT_DIM / 8;
  for (int idx = bid * 256 + t; idx < cchunks; idx += nblk * 256) {
    int tk = idx >> 7;
    int cc = (idx & 127) * 8;
    float ga = gates[2 * tk];
    float gb = gates[2 * tk + 1];
    short8 s0 = *(const short8*)&slot_out[(size_t)(2 * tk) * OUT_DIM + cc];
    short8 s1 = *(const short8*)&slot_out[(size_t)(2 * tk + 1) * OUT_DIM + cc];
    f32x4 o0, o1;
#pragma unroll
    for (int j = 0; j < 4; ++j) {
      o0[j] = ga * bf2f((u16)s0[j])     + gb * bf2f((u16)s1[j]);
      o1[j] = ga * bf2f((u16)s0[4 + j]) + gb * bf2f((u16)s1[4 + j]);
    }
    f32x4* dst = (f32x4*)(out + (size_t)tk * OUT_DIM + cc);
    dst[0] = o0; dst[1] = o1;
  }
}

// ---------------------------------------------------------------------------
// Fallback path (R5, verified 260us): convert + GEMM->slot + combine.
// ---------------------------------------------------------------------------
__global__ __launch_bounds__(256) void convert_two(
    const float* __restrict__ X, const float* __restrict__ W,
    u16* __restrict__ Xb, u16* __restrict__ Wb, int xblocks, int xn8, int wn8) {
  const float* src; u16* dst; int i, n8;
  if ((int)blockIdx.x < xblocks) {
    i = blockIdx.x * 256 + threadIdx.x; src = X; dst = Xb; n8 = xn8;
  } else {
    i = (blockIdx.x - xblocks) * 256 + threadIdx.x; src = W; dst = Wb; n8 = wn8;
  }
  if (i >= n8) return;
  const f32x4* s = (const f32x4*)src + (size_t)i * 2;
  f32x4 v0 = s[0], v1 = s[1];
  short8 o;
#pragma unroll
  for (int j = 0; j < 4; ++j) {
    o[j]     = (short)f2bf(v0[j]);
    o[4 + j] = (short)f2bf(v1[j]);
  }
  *(short8*)(dst + (size_t)i * 8) = o;
}

__global__ __launch_bounds__(256) void moe_gemm_slot(
    const u16* __restrict__ Xb, const u16* __restrict__ Wb,
    const int* __restrict__ kptr, const int* __restrict__ ssi_raw,
    const int* __restrict__ eoff_raw, u16* __restrict__ slot_out)
{
  __shared__ __align__(16) u16 smem[BM * BN];
  u16* As = smem;
  u16* Bs = smem + BM * BK;

  const bool is64 = (eoff_raw[7] != S_SLOTS);
  int expert, rs, re;
  if (!derive_tile(eoff_raw, is64, blockIdx.x, expert, rs, re)) return;
  const int rcount = re - rs;

  const int n0   = blockIdx.y * BN;
  const int kdiv = kptr[0];
  const int t    = threadIdx.x;

  const int r0 = t >> 2;
  const int r1 = (t + 256) >> 2;
  const int cg2 = (t & 3) * 8;

  int g0 = rs + r0; if (g0 >= re) g0 = re - 1;
  int g1 = rs + r1; if (g1 >= re) g1 = re - 1;
  const int tok0 = (is64 ? ssi_raw[2 * g0] : ssi_raw[g0]) / kdiv;
  const int tok1 = (is64 ? ssi_raw[2 * g1] : ssi_raw[g1]) / kdiv;

  const u16* a0 = Xb + (size_t)tok0 * IN_DIM + cg2;
  const u16* a1 = Xb + (size_t)tok1 * IN_DIM + cg2;
  const u16* wbp = Wb + (size_t)expert * OUT_DIM * IN_DIM;
  const u16* b0 = wbp + (size_t)(n0 + r0) * IN_DIM + cg2;
  const u16* b1 = wbp + (size_t)(n0 + r1) * IN_DIM + cg2;

  f32x4 acc[4][4];
#pragma unroll
  for (int i = 0; i < 4; ++i)
#pragma unroll
    for (int j = 0; j < 4; ++j)
      acc[i][j] = (f32x4){0.f, 0.f, 0.f, 0.f};

  const int wave = t >> 6;
  const int lane = t & 63;
  const int wm = (wave >> 1) * 64;
  const int wn = (wave & 1) * 64;
  const int lr = lane & 15;
  const int lk = (lane >> 4) * 8;

  for (int k0 = 0; k0 < IN_DIM; k0 += BK) {
    GLD_LDS16(a0 + k0, As + (size_t)t * 8);
    GLD_LDS16(a1 + k0, As + (size_t)(t + 256) * 8);
    GLD_LDS16(b0 + k0, Bs + (size_t)t * 8);
    GLD_LDS16(b1 + k0, Bs + (size_t)(t + 256) * 8);
    __syncthreads();

    short8 af[4], bfv[4];
#pragma unroll
    for (int mi = 0; mi < 4; ++mi)
      af[mi] = *(const short8*)&As[(wm + mi * 16 + lr) * BK + lk];
#pragma unroll
    for (int ni = 0; ni < 4; ++ni)
      bfv[ni] = *(const short8*)&Bs[(wn + ni * 16 + lr) * BK + lk];

#pragma unroll
    for (int mi = 0; mi < 4; ++mi)
#pragma unroll
      for (int ni = 0; ni < 4; ++ni)
        acc[mi][ni] = __builtin_amdgcn_mfma_f32_16x16x32_bf16(
            af[mi], bfv[ni], acc[mi][ni], 0, 0, 0);

    __syncthreads();
  }

  u16* Cs = smem;
#pragma unroll
  for (int mi = 0; mi < 4; ++mi)
#pragma unroll
    for (int ni = 0; ni < 4; ++ni)
#pragma unroll
      for (int r = 0; r < 4; ++r) {
        int row = wm + mi * 16 + (lane >> 4) * 4 + r;
        int col = wn + ni * 16 + lr;
        Cs[row * BN + col] = f2bf(acc[mi][ni][r]);
      }
  __syncthreads();

  const int crow = t >> 4;
  const int ccol = (t & 15) * 8;
#pragma unroll
  for (int i = 0; i < 8; ++i) {
    int row = i * 16 + crow;
    if (row < rcount) {
      *(short8*)&slot_out[(size_t)(rs + row) * OUT_DIM + n0 + ccol] =
          *(const short8*)&Cs[row * BN + ccol];
    }
  }
}

__global__ __launch_bounds__(256) void combine_k(
    const u16* __restrict__ slot_out, const float* __restrict__ gates,
    float* __restrict__ out)
{
  int idx = blockIdx.x * 256 + threadIdx.x;
  if (idx >= N_TOKENS * OUT_DIM / 8) return;
  int tk = idx >> 7;
  int cc = (idx & 127) * 8;
  float ga = gates[2 * tk];
  float gb = gates[2 * tk + 1];
  short8 s0 = *(const short8*)&slot_out[(size_t)(2 * tk) * OUT_DIM + cc];
  short8 s1 = *(const short8*)&slot_out[(size_t)(2 * tk + 1) * OUT_DIM + cc];
  f32x4 o0, o1;
#pragma unroll
  for (int j = 0; j < 4; ++j) {
    o0[j] = ga * bf2f((u16)s0[j])     + gb * bf2f((u16)s1[j]);
    o1[j] = ga * bf2f((u16)s0[4 + j]) + gb * bf2f((u16)s1[4 + j]);
  }
  f32x4* dst = (f32x4*)(out + (size_t)tk * OUT_DIM + cc);
  dst[0] = o0; dst[1] = o1;
}

// Last-resort (R3, verified): fp32 staging + inline convert + atomics, no ws.
__global__ __launch_bounds__(256) void moe_gemm_fused_f32(
    const float* __restrict__ X, const float* __restrict__ W,
    const float* __restrict__ gates, const int* __restrict__ kptr,
    const int*   __restrict__ ssi_raw, const int* __restrict__ eoff_raw,
    float*       __restrict__ out)
{
  __shared__ __align__(16) u16 As[BM * BK];
  __shared__ __align__(16) u16 Bs[BN * BK];

  const bool is64 = (eoff_raw[7] != S_SLOTS);
  int expert, rs, re;
  if (!derive_tile(eoff_raw, is64, blockIdx.x, expert, rs, re)) return;
  const int rcount = re - rs;

  const int n0   = blockIdx.y * BN;
  const int kdiv = kptr[0];
  const int t    = threadIdx.x;

  const float* arow[4];
  const float* brow[4];
  int lofs[4];
#pragma unroll
  for (int i = 0; i < 4; ++i) {
    int c = t + 256 * i;
    int r = c >> 3;
    int col4 = (c & 7) * 4;
    int g = rs + r; if (g >= re) g = re - 1;
    int sval = is64 ? ssi_raw[2 * g] : ssi_raw[g];
    int tok  = sval / kdiv;
    arow[i] = X + (size_t)tok * IN_DIM + col4;
    brow[i] = W + ((size_t)expert * OUT_DIM + n0 + r) * IN_DIM + col4;
    lofs[i] = r * BK + col4;
  }

  f32x4 acc[4][4];
#pragma unroll
  for (int i = 0; i < 4; ++i)
#pragma unroll
    for (int j = 0; j < 4; ++j)
      acc[i][j] = (f32x4){0.f, 0.f, 0.f, 0.f};

  const int wave = t >> 6;
  const int lane = t & 63;
  const int wm = (wave >> 1) * 64;
  const int wn = (wave & 1) * 64;
  const int lr = lane & 15;
  const int lk = (lane >> 4) * 8;

  for (int k0 = 0; k0 < IN_DIM; k0 += BK) {
    f32x4 a[4], b[4];
#pragma unroll
    for (int i = 0; i < 4; ++i) {
      a[i] = *(const f32x4*)(arow[i] + k0);
      b[i] = *(const f32x4*)(brow[i] + k0);
    }
    __syncthreads();
#pragma unroll
    for (int i = 0; i < 4; ++i) {
      short4v av, bv;
#pragma unroll
      for (int j = 0; j < 4; ++j) {
        av[j] = (short)f2bf(a[i][j]);
        bv[j] = (short)f2bf(b[i][j]);
      }
      *(short4v*)&As[lofs[i]] = av;
      *(short4v*)&Bs[lofs[i]] = bv;
    }
    __syncthreads();

    short8 af[4], bfv[4];
#pragma unroll
    for (int mi = 0; mi < 4; ++mi)
      af[mi] = *(const short8*)&As[(wm + mi * 16 + lr) * BK + lk];
#pragma unroll
    for (int ni = 0; ni < 4; ++ni)
      bfv[ni] = *(const short8*)&Bs[(wn + ni * 16 + lr) * BK + lk];

#pragma unroll
    for (int mi = 0; mi < 4; ++mi)
#pragma unroll
      for (int ni = 0; ni < 4; ++ni)
        acc[mi][ni] = __builtin_amdgcn_mfma_f32_16x16x32_bf16(
            af[mi], bfv[ni], acc[mi][ni], 0, 0, 0);
  }

#pragma unroll
  for (int mi = 0; mi < 4; ++mi) {
#pragma unroll
    for (int r = 0; r < 4; ++r) {
      int row = wm + mi * 16 + (lane >> 4) * 4 + r;
      if (row < rcount) {
        int slot  = rs + row;
        int token = slot / kdiv;
        float g   = gates[slot];
        float* dst = out + (size_t)token * OUT_DIM + n0;
#pragma unroll
        for (int ni = 0; ni < 4; ++ni) {
          int col = wn + ni * 16 + lr;
          atomicAdd(dst + col, g * acc[mi][ni][r]);
        }
      }
    }
  }
}

// ---------------------------------------------------------------------------
extern "C" void kernel_launch(void* const* d_in, const int* in_sizes, int n_in,
                              void* d_out, int out_size, void* d_ws, size_t ws_size,
                              hipStream_t stream) {
  const float* X     = (const float*)d_in[0];
  const float* W     = (const float*)d_in[1];
  const float* gates = (const float*)d_in[2];
  const int*   kptr  = (const int*)d_in[3];
  // d_in[4] = sorted_expert_idxs (unused; experts derived from offsets)
  const int*   ssi   = (const int*)d_in[5];
  const int*   eoff  = (const int*)d_in[6];
  float* out = (float*)d_out;

  const size_t x_elems = (size_t)N_TOKENS * IN_DIM;            // 16.7M
  const size_t w_elems = (size_t)N_EXPERTS * OUT_DIM * IN_DIM; // 8.4M
  const size_t s_elems = (size_t)S_SLOTS * OUT_DIM;            // 33.5M
  const size_t need_full = (x_elems + w_elems + s_elems) * sizeof(u16); // 116 MB

  if (ws_size >= need_full) {
    u16* Xb = (u16*)d_ws;
    u16* Wb = Xb + x_elems;
    u16* slot_out = Wb + w_elems;

    // Cooperative single-dispatch path.
    int maxB = 0;
    hipError_t oe = hipOccupancyMaxActiveBlocksPerMultiprocessor(
        &maxB, (const void*)moe_fused, 256, 0);
    int nblk = (oe == hipSuccess && maxB > 0) ? maxB * 256 : 0;
    if (nblk > 1056) nblk = 1056;   // 2112 jobs / 1056 = exactly 2 per block

    hipError_t ce = hipErrorUnknown;
    if (nblk >= 256) {
      void* kargs[] = {(void*)&X, (void*)&W, (void*)&gates, (void*)&kptr,
                       (void*)&ssi, (void*)&eoff, (void*)&Xb, (void*)&Wb,
                       (void*)&slot_out, (void*)&out, (void*)&nblk};
      ce = hipLaunchCooperativeKernel((const void*)moe_fused, dim3(nblk),
                                      dim3(256), kargs, 0, stream);
    }
    if (ce == hipSuccess) return;
    (void)hipGetLastError();   // clear, fall through to 3-node path

    const int xn8 = (int)(x_elems / 8), wn8 = (int)(w_elems / 8);
    const int xblocks = (xn8 + 255) / 256, wblocks = (wn8 + 255) / 256;
    hipLaunchKernelGGL(convert_two, dim3(xblocks + wblocks), dim3(256), 0,
                       stream, X, W, Xb, Wb, xblocks, xn8, wn8);
    hipLaunchKernelGGL(moe_gemm_slot, dim3(MAX_TILES, NGROUPS), dim3(256),
                       0, stream, Xb, Wb, kptr, ssi, eoff, slot_out);
    const int nchunks = N_TOKENS * OUT_DIM / 8;
    hipLaunchKernelGGL(combine_k, dim3(nchunks / 256), dim3(256), 0, stream,
                       slot_out, gates, out);
  } else {
    hipMemsetAsync(d_out, 0, (size_t)out_size * sizeof(float), stream);
    hipLaunchKernelGGL(moe_gemm_fused_f32, dim3(MAX_TILES, NGROUPS), dim3(256),
                       0, stream, X, W, gates, kptr, ssi, eoff, out);
  }
}

// Round 7
// 243.659 us; speedup vs baseline: 1.7784x; 1.7784x over previous
//
#include <hip/hip_runtime.h>
#include <stdint.h>

#define N_EXPERTS 8
#define IN_DIM    1024
#define OUT_DIM   1024
#define N_TOKENS  16384
#define S_SLOTS   (N_TOKENS * 2)
#define BM 128
#define BN 128
#define BK 32
#define MAX_TILES 264   // sum ceil(cnt_e/128) <= 256 + 8
#define NGROUPS   (OUT_DIM / BN)   // 8

typedef unsigned short u16;
using short4v = __attribute__((ext_vector_type(4))) short;
using short8  = __attribute__((ext_vector_type(8))) short;
using f32x4   = __attribute__((ext_vector_type(4))) float;

__device__ __forceinline__ u16 f2bf(float f) {
  uint32_t x = __builtin_bit_cast(uint32_t, f);
  uint32_t r = x + 0x7fffu + ((x >> 16) & 1u);   // round-to-nearest-even
  return (u16)(r >> 16);
}
__device__ __forceinline__ float bf2f(u16 u) {
  uint32_t x = ((uint32_t)u) << 16;
  return __builtin_bit_cast(float, x);
}

#define GLD_LDS16(g, l) __builtin_amdgcn_global_load_lds(            \
    (const __attribute__((address_space(1))) void*)(g),              \
    (__attribute__((address_space(3))) void*)(l), 16, 0, 0)

// ---------------------------------------------------------------------------
// Shared tile derivation (slots sorted by expert; <=264 M-tiles)
// ---------------------------------------------------------------------------
__device__ __forceinline__ bool derive_tile(const int* eoff_raw, bool is64,
                                            int bx, int& expert, int& rs, int& re) {
  int rem = bx, prev = 0;
  expert = -1;
  for (int e = 0; e < N_EXPERTS; ++e) {
    int end = is64 ? eoff_raw[2 * e] : eoff_raw[e];
    int cnt = end - prev;
    int nt  = (cnt + BM - 1) / BM;
    if (expert < 0) {
      if (rem < nt) {
        expert = e;
        rs = prev + rem * BM;
        re = (rs + BM < end) ? (rs + BM) : end;
      } else {
        rem -= nt;
      }
    }
    prev = end;
  }
  return expert >= 0;
}

// ---------------------------------------------------------------------------
// Node 1: fp32->bf16 convert of X and W, PLUS zeroing of straddle-pair token
// rows (odd tile starts) so the GEMM can atomicAdd edge contributions.
// ---------------------------------------------------------------------------
__global__ __launch_bounds__(256) void convert_zero(
    const float* __restrict__ X, const float* __restrict__ W,
    u16* __restrict__ Xb, u16* __restrict__ Wb,
    const int* __restrict__ eoff_raw,
    float* __restrict__ out,
    int xblocks, int wblocks, int xn8, int wn8) {
  int bx = blockIdx.x;
  if (bx < xblocks + wblocks) {
    const float* src; u16* dst; int i, n8;
    if (bx < xblocks) { i = bx * 256 + threadIdx.x; src = X; dst = Xb; n8 = xn8; }
    else { i = (bx - xblocks) * 256 + threadIdx.x; src = W; dst = Wb; n8 = wn8; }
    if (i >= n8) return;
    const f32x4* s = (const f32x4*)src + (size_t)i * 2;
    f32x4 v0 = s[0], v1 = s[1];
    short8 o;
#pragma unroll
    for (int j = 0; j < 4; ++j) {
      o[j]     = (short)f2bf(v0[j]);
      o[4 + j] = (short)f2bf(v1[j]);
    }
    *(short8*)(dst + (size_t)i * 8) = o;
  } else {
    // straddle-row zeroing: tile start rs odd -> pair (rs-1, rs) straddles
    // tiles -> token rs>>1 gets both contributions via atomicAdd.
    int bx2 = bx - xblocks - wblocks;
    const bool is64 = (eoff_raw[7] != S_SLOTS);
    int expert, rs, re;
    if (!derive_tile(eoff_raw, is64, bx2, expert, rs, re)) return;
    if (rs & 1) {
      f32x4 z = (f32x4){0.f, 0.f, 0.f, 0.f};
      *(f32x4*)(out + (size_t)(rs >> 1) * OUT_DIM + threadIdx.x * 4) = z;
    }
  }
}

// ---------------------------------------------------------------------------
// Node 2: grouped GEMM with fused gate-combine epilogue.
//   complete pairs (both slots in tile): out[t] = g0*C[r] + g1*C[r+1], plain
//   fp32 stores. Edge rows (partner outside tile): fp32 atomicAdd into the
//   pre-zeroed token row.
// ---------------------------------------------------------------------------
__global__ __launch_bounds__(256) void moe_gemm_out(
    const u16*   __restrict__ Xb,       // [N_TOKENS, IN_DIM] bf16 (ws)
    const u16*   __restrict__ Wb,       // [E, OUT_DIM, IN_DIM] bf16 (ws)
    const float* __restrict__ gates,    // [S] fp32
    const int*   __restrict__ kptr,
    const int*   __restrict__ ssi_raw,  // int32 or int64
    const int*   __restrict__ eoff_raw, // int32 or int64
    float*       __restrict__ out)      // [N_TOKENS, OUT_DIM] fp32
{
  __shared__ __align__(16) u16 smem[BM * BN];   // 32 KB, aliased As/Bs <-> Cs
  u16* As = smem;             // BM*BK
  u16* Bs = smem + BM * BK;   // BN*BK

  const bool is64 = (eoff_raw[7] != S_SLOTS);
  int expert, rs, re;
  if (!derive_tile(eoff_raw, is64, blockIdx.x, expert, rs, re)) return;
  const int rcount = re - rs;

  const int n0   = blockIdx.y * BN;
  const int kdiv = kptr[0];
  const int t    = threadIdx.x;

  // staging: 512 16B-chunks/slab; thread handles chunks t and t+256.
  const int r0 = t >> 2;
  const int r1 = (t + 256) >> 2;
  const int cg = (t & 3) * 8;

  int g0 = rs + r0; if (g0 >= re) g0 = re - 1;
  int g1 = rs + r1; if (g1 >= re) g1 = re - 1;
  const int tok0 = (is64 ? ssi_raw[2 * g0] : ssi_raw[g0]) / kdiv;
  const int tok1 = (is64 ? ssi_raw[2 * g1] : ssi_raw[g1]) / kdiv;

  const u16* a0 = Xb + (size_t)tok0 * IN_DIM + cg;
  const u16* a1 = Xb + (size_t)tok1 * IN_DIM + cg;
  const u16* wbp = Wb + (size_t)expert * OUT_DIM * IN_DIM;
  const u16* b0 = wbp + (size_t)(n0 + r0) * IN_DIM + cg;
  const u16* b1 = wbp + (size_t)(n0 + r1) * IN_DIM + cg;

  f32x4 acc[4][4];
#pragma unroll
  for (int i = 0; i < 4; ++i)
#pragma unroll
    for (int j = 0; j < 4; ++j)
      acc[i][j] = (f32x4){0.f, 0.f, 0.f, 0.f};

  const int wave = t >> 6;
  const int lane = t & 63;
  const int wm = (wave >> 1) * 64;
  const int wn = (wave & 1) * 64;
  const int lr = lane & 15;
  const int lk = (lane >> 4) * 8;

  for (int k0 = 0; k0 < IN_DIM; k0 += BK) {
    GLD_LDS16(a0 + k0, As + (size_t)t * 8);
    GLD_LDS16(a1 + k0, As + (size_t)(t + 256) * 8);
    GLD_LDS16(b0 + k0, Bs + (size_t)t * 8);
    GLD_LDS16(b1 + k0, Bs + (size_t)(t + 256) * 8);
    __syncthreads();   // drains vmcnt -> LDS valid

    short8 af[4], bfv[4];
#pragma unroll
    for (int mi = 0; mi < 4; ++mi)
      af[mi] = *(const short8*)&As[(wm + mi * 16 + lr) * BK + lk];
#pragma unroll
    for (int ni = 0; ni < 4; ++ni)
      bfv[ni] = *(const short8*)&Bs[(wn + ni * 16 + lr) * BK + lk];

#pragma unroll
    for (int mi = 0; mi < 4; ++mi)
#pragma unroll
      for (int ni = 0; ni < 4; ++ni)
        acc[mi][ni] = __builtin_amdgcn_mfma_f32_16x16x32_bf16(
            af[mi], bfv[ni], acc[mi][ni], 0, 0, 0);

    __syncthreads();
  }

  // ---- Epilogue 1: repack C (col=lane&15, row=(lane>>4)*4+reg) into Cs ----
  u16* Cs = smem;   // aliases As/Bs (barrier above makes this safe)
#pragma unroll
  for (int mi = 0; mi < 4; ++mi)
#pragma unroll
    for (int ni = 0; ni < 4; ++ni)
#pragma unroll
      for (int r = 0; r < 4; ++r) {
        int row = wm + mi * 16 + (lane >> 4) * 4 + r;
        int col = wn + ni * 16 + lr;
        Cs[row * BN + col] = f2bf(acc[mi][ni][r]);
      }
  __syncthreads();

  // ---- Epilogue 2: gate-combine complete pairs, plain fp32 stores --------
  const int s0     = rs + (rs & 1);        // first even slot in tile
  const int npairs = (re > s0) ? ((re - s0) >> 1) : 0;
  for (int it = t; it < npairs * 16; it += 256) {
    int p  = it >> 4;
    int cc = (it & 15) * 8;
    int lr0 = (s0 - rs) + 2 * p;           // local row of even slot
    float ga = gates[s0 + 2 * p];
    float gb = gates[s0 + 2 * p + 1];
    short8 c0 = *(const short8*)&Cs[lr0 * BN + cc];
    short8 c1 = *(const short8*)&Cs[(lr0 + 1) * BN + cc];
    f32x4 o0, o1;
#pragma unroll
    for (int j = 0; j < 4; ++j) {
      o0[j] = ga * bf2f((u16)c0[j])     + gb * bf2f((u16)c1[j]);
      o1[j] = ga * bf2f((u16)c0[4 + j]) + gb * bf2f((u16)c1[4 + j]);
    }
    float* dst = out + (size_t)((s0 + 2 * p) >> 1) * OUT_DIM + n0 + cc;
    *(f32x4*)dst       = o0;
    *((f32x4*)dst + 1) = o1;
  }

  // ---- Epilogue 3: edge rows (partner slot outside tile) -> atomicAdd ----
  if (rs & 1) {            // local row 0 = slot rs (odd), token rs>>1
    float g = gates[rs];
    float* dst = out + (size_t)(rs >> 1) * OUT_DIM + n0;
    for (int c = t; c < BN; c += 256)
      atomicAdd(dst + c, g * bf2f(Cs[c]));
  }
  if (re & 1) {            // last row = slot re-1 (even), partner re outside
    int lrow = re - 1 - rs;
    float g = gates[re - 1];
    float* dst = out + (size_t)((re - 1) >> 1) * OUT_DIM + n0;
    for (int c = t; c < BN; c += 256)
      atomicAdd(dst + c, g * bf2f(Cs[lrow * BN + c]));
  }
}

// ---------------------------------------------------------------------------
// Last-resort fallback (R3, verified): fp32 staging + inline convert + atomics.
// ---------------------------------------------------------------------------
__global__ __launch_bounds__(256) void moe_gemm_fused_f32(
    const float* __restrict__ X, const float* __restrict__ W,
    const float* __restrict__ gates, const int* __restrict__ kptr,
    const int*   __restrict__ ssi_raw, const int* __restrict__ eoff_raw,
    float*       __restrict__ out)
{
  __shared__ __align__(16) u16 As[BM * BK];
  __shared__ __align__(16) u16 Bs[BN * BK];

  const bool is64 = (eoff_raw[7] != S_SLOTS);
  int expert, rs, re;
  if (!derive_tile(eoff_raw, is64, blockIdx.x, expert, rs, re)) return;
  const int rcount = re - rs;

  const int n0   = blockIdx.y * BN;
  const int kdiv = kptr[0];
  const int t    = threadIdx.x;

  const float* arow[4];
  const float* brow[4];
  int lofs[4];
#pragma unroll
  for (int i = 0; i < 4; ++i) {
    int c = t + 256 * i;
    int r = c >> 3;
    int col4 = (c & 7) * 4;
    int g = rs + r; if (g >= re) g = re - 1;
    int sval = is64 ? ssi_raw[2 * g] : ssi_raw[g];
    int tok  = sval / kdiv;
    arow[i] = X + (size_t)tok * IN_DIM + col4;
    brow[i] = W + ((size_t)expert * OUT_DIM + n0 + r) * IN_DIM + col4;
    lofs[i] = r * BK + col4;
  }

  f32x4 acc[4][4];
#pragma unroll
  for (int i = 0; i < 4; ++i)
#pragma unroll
    for (int j = 0; j < 4; ++j)
      acc[i][j] = (f32x4){0.f, 0.f, 0.f, 0.f};

  const int wave = t >> 6;
  const int lane = t & 63;
  const int wm = (wave >> 1) * 64;
  const int wn = (wave & 1) * 64;
  const int lr = lane & 15;
  const int lk = (lane >> 4) * 8;

  for (int k0 = 0; k0 < IN_DIM; k0 += BK) {
    f32x4 a[4], b[4];
#pragma unroll
    for (int i = 0; i < 4; ++i) {
      a[i] = *(const f32x4*)(arow[i] + k0);
      b[i] = *(const f32x4*)(brow[i] + k0);
    }
    __syncthreads();
#pragma unroll
    for (int i = 0; i < 4; ++i) {
      short4v av, bv;
#pragma unroll
      for (int j = 0; j < 4; ++j) {
        av[j] = (short)f2bf(a[i][j]);
        bv[j] = (short)f2bf(b[i][j]);
      }
      *(short4v*)&As[lofs[i]] = av;
      *(short4v*)&Bs[lofs[i]] = bv;
    }
    __syncthreads();

    short8 af[4], bfv[4];
#pragma unroll
    for (int mi = 0; mi < 4; ++mi)
      af[mi] = *(const short8*)&As[(wm + mi * 16 + lr) * BK + lk];
#pragma unroll
    for (int ni = 0; ni < 4; ++ni)
      bfv[ni] = *(const short8*)&Bs[(wn + ni * 16 + lr) * BK + lk];

#pragma unroll
    for (int mi = 0; mi < 4; ++mi)
#pragma unroll
      for (int ni = 0; ni < 4; ++ni)
        acc[mi][ni] = __builtin_amdgcn_mfma_f32_16x16x32_bf16(
            af[mi], bfv[ni], acc[mi][ni], 0, 0, 0);
  }

#pragma unroll
  for (int mi = 0; mi < 4; ++mi) {
#pragma unroll
    for (int r = 0; r < 4; ++r) {
      int row = wm + mi * 16 + (lane >> 4) * 4 + r;
      if (row < rcount) {
        int slot  = rs + row;
        int token = slot / kdiv;
        float g   = gates[slot];
        float* dst = out + (size_t)token * OUT_DIM + n0;
#pragma unroll
        for (int ni = 0; ni < 4; ++ni) {
          int col = wn + ni * 16 + lr;
          atomicAdd(dst + col, g * acc[mi][ni][r]);
        }
      }
    }
  }
}

// ---------------------------------------------------------------------------
extern "C" void kernel_launch(void* const* d_in, const int* in_sizes, int n_in,
                              void* d_out, int out_size, void* d_ws, size_t ws_size,
                              hipStream_t stream) {
  const float* X     = (const float*)d_in[0];
  const float* W     = (const float*)d_in[1];
  const float* gates = (const float*)d_in[2];
  const int*   kptr  = (const int*)d_in[3];
  // d_in[4] = sorted_expert_idxs (unused; experts derived from offsets)
  const int*   ssi   = (const int*)d_in[5];
  const int*   eoff  = (const int*)d_in[6];
  float* out = (float*)d_out;

  const size_t x_elems = (size_t)N_TOKENS * IN_DIM;            // 16.7M
  const size_t w_elems = (size_t)N_EXPERTS * OUT_DIM * IN_DIM; // 8.4M
  const size_t need = (x_elems + w_elems) * sizeof(u16);       // 50 MB

  if (ws_size >= need) {
    u16* Xb = (u16*)d_ws;
    u16* Wb = Xb + x_elems;
    const int xn8 = (int)(x_elems / 8), wn8 = (int)(w_elems / 8);
    const int xblocks = (xn8 + 255) / 256, wblocks = (wn8 + 255) / 256;
    hipLaunchKernelGGL(convert_zero, dim3(xblocks + wblocks + MAX_TILES),
                       dim3(256), 0, stream, X, W, Xb, Wb, eoff, out,
                       xblocks, wblocks, xn8, wn8);
    hipLaunchKernelGGL(moe_gemm_out, dim3(MAX_TILES, NGROUPS), dim3(256),
                       0, stream, Xb, Wb, gates, kptr, ssi, eoff, out);
  } else {
    hipMemsetAsync(d_out, 0, (size_t)out_size * sizeof(float), stream);
    hipLaunchKernelGGL(moe_gemm_fused_f32, dim3(MAX_TILES, NGROUPS), dim3(256),
                       0, stream, X, W, gates, kptr, ssi, eoff, out);
  }
}